// Round 1
// baseline (347.821 us; speedup 1.0000x reference)
//
#include <hip/hip_runtime.h>
#include <hip/hip_bf16.h>
#include <math.h>

#define NNODE  200000
#define DIM    64
#define NF     4
#define NLAYER 2
#define KK     32
#define BB     1024

typedef __bf16 bf16x8 __attribute__((ext_vector_type(8)));
typedef __bf16 bf16x4 __attribute__((ext_vector_type(4)));
typedef float  f32x4  __attribute__((ext_vector_type(4)));

// X row stride in bf16 elements: 128 + 8 pad -> 272 B (16B-aligned; MFMA
// fragment reads stay 2-way-only bank aliasing = free per m136).
// FSKEW: extra 8-element (16 B) skew per factor block — breaks the
// 128 B-periodic factor stride so the 32 B/lane gather writes drop from
// 8-way to ~4-way conflicts while keeping b128 alignment.
#define XSTRIDE 136
#define FSKEW   8

// prep: (a) node_emb f32 -> bf16 table. Streams 204.8 MB once per launch
// (poison-safe: ws is re-derived every call) and leaves the 102.4 MB bf16
// table L3-resident for the gather kernel. (b) W1 -> W1T bf16 (64 x 128).
__global__ __launch_bounds__(256) void prep(
    const float* __restrict__ ne, __bf16* __restrict__ nbf,
    const float* __restrict__ W1, __bf16* __restrict__ w1t)
{
    const size_t t = (size_t)blockIdx.x * 256 + threadIdx.x;
    const size_t i = t * 8;
    f32x4 a = *(const f32x4*)(ne + i);
    f32x4 b = *(const f32x4*)(ne + i + 4);
    bf16x8 o;
#pragma unroll
    for (int u = 0; u < 4; ++u) { o[u] = (__bf16)a[u]; o[u + 4] = (__bf16)b[u]; }
    *(bf16x8*)(nbf + i) = o;
    if (t < 2 * DIM * DIM) {   // 8192: w1t[d*128+i] = W1[i][d]
        const int d = (int)t >> 7, ii = (int)t & 127;
        w1t[t] = (__bf16)W1[ii * DIM + d];
    }
}

// One block per (tower, b, layer). 256 threads = 4 waves; wave w = factor f.
// 4 blocks/CU (LDS 35.4 KB x 4 = 142 KB; VGPR cap 128).
__global__ __launch_bounds__(256, 4) void kgat_mfma(
    const __bf16* __restrict__ nbf,
    const float* __restrict__ node_emb,
    const __bf16* __restrict__ w1t,
    const float* __restrict__ b1,
    const float* __restrict__ W2,
    const int*   __restrict__ users,
    const int*   __restrict__ items,
    const int*   __restrict__ users_triple,
    const int*   __restrict__ items_triple,
    float*       __restrict__ out)
{
    __shared__ __bf16 Xs[128 * XSTRIDE + NF * FSKEW];
    __shared__ float  logitS[128];

    const int bid   = blockIdx.x;          // 0..4095
    const int tower = bid >> 11;
    const int b     = (bid >> 1) & 1023;
    const int layer = bid & 1;
    const int tid   = threadIdx.x;
    const int w     = tid >> 6;            // wave id = factor
    const int lane  = tid & 63;
    const int m16   = lane & 15;
    const int quad  = lane >> 4;

    const int* __restrict__ triple = tower ? items_triple : users_triple;
    const int* __restrict__ idxarr = tower ? items : users;

    const int hbase = ((b * 3 + 0) * NLAYER + layer) * KK;
    const int tbase = ((b * 3 + 2) * NLAYER + layer) * KK;

    // ---- Gather: 64 bf16 rows (32 h + 32 t), 512 B each, from the L3-hot
    // bf16 node table. 16 lanes/row, 32 B/lane, 8 loads in flight/thread. ----
    {
        const int m = tid & 15;
        const int g = tid >> 4;
        int kv[4], chv[4], idxv[4];
#pragma unroll
        for (int r = 0; r < 4; ++r) {
            const int task = r * 16 + g;           // 0..63
            kv[r]   = task & 31;
            chv[r]  = task >> 5;                   // 0 = h, 1 = t
            idxv[r] = triple[(chv[r] ? tbase : hbase) + kv[r]];
        }
        bf16x8 gv[4][2];
#pragma unroll
        for (int r = 0; r < 4; ++r) {
            const __bf16* __restrict__ src = nbf + (size_t)idxv[r] * (NF * DIM) + m * 16;
            gv[r][0] = *(const bf16x8*)(src);
            gv[r][1] = *(const bf16x8*)(src + 8);
        }
        // lane m holds elems [m*16, m*16+16) of the 256-elem row:
        // factor f = m>>2, within-factor dims [(m&3)*16, +16)
        const int f = m >> 2, c = m & 3;
#pragma unroll
        for (int r = 0; r < 4; ++r) {
            __bf16* dst = &Xs[(f * 32 + kv[r]) * XSTRIDE + f * FSKEW + chv[r] * 64 + c * 16];
            *(bf16x8*)(dst)     = gv[r][0];
            *(bf16x8*)(dst + 8) = gv[r][1];
        }
    }

    // ---- B fragments (W1): B[k][n], n = nt*16 + m16, k = kt*32 + quad*8 + j.
    // 16 KB, identical for every block -> L1/L2-hot. Loaded after the gather
    // writes so the 64 Bf VGPRs don't overlap the gather's in-flight data
    // (keeps us under the 128-VGPR cap for 4 waves/SIMD). ----
    bf16x8 Bf[4][4];
#pragma unroll
    for (int nt = 0; nt < 4; ++nt)
#pragma unroll
        for (int kt = 0; kt < 4; ++kt)
            Bf[nt][kt] = *(const bf16x8*)(w1t + (nt * 16 + m16) * 128 + kt * 32 + quad * 8);

    __syncthreads();

    // ---- MFMA: wave w computes hid rows [w*32, w*32+32), all 64 cols ----
    f32x4 C[2][4];   // [m-tile][n-tile]
#pragma unroll
    for (int mt = 0; mt < 2; ++mt)
#pragma unroll
        for (int nt = 0; nt < 4; ++nt) C[mt][nt] = (f32x4)(0.f);

    const __bf16* Arow0 = &Xs[(w * 32 + m16) * XSTRIDE + w * FSKEW];        // m-tile 0
    const __bf16* Arow1 = &Xs[(w * 32 + 16 + m16) * XSTRIDE + w * FSKEW];   // m-tile 1
#pragma unroll
    for (int kt = 0; kt < 4; ++kt) {
        bf16x8 A0 = *(const bf16x8*)(Arow0 + kt * 32 + quad * 8);
        bf16x8 A1 = *(const bf16x8*)(Arow1 + kt * 32 + quad * 8);
#pragma unroll
        for (int nt = 0; nt < 4; ++nt) {
            C[0][nt] = __builtin_amdgcn_mfma_f32_16x16x32_bf16(A0, Bf[nt][kt], C[0][nt], 0, 0, 0);
            C[1][nt] = __builtin_amdgcn_mfma_f32_16x16x32_bf16(A1, Bf[nt][kt], C[1][nt], 0, 0, 0);
        }
    }

    // ---- Epilogue: logits[row] = sum_d relu(hid + b1) * W2  (b2 cancels) ----
    float b1v[4], w2v[4];
#pragma unroll
    for (int nt = 0; nt < 4; ++nt) {
        b1v[nt] = b1[nt * 16 + m16];
        w2v[nt] = W2[nt * 16 + m16];
    }
    float lsum[2][4];   // [mt][reg]; C row = mt*16 + quad*4 + reg, col = nt*16 + m16
#pragma unroll
    for (int mt = 0; mt < 2; ++mt)
#pragma unroll
        for (int r = 0; r < 4; ++r) {
            float s = 0.f;
#pragma unroll
            for (int nt = 0; nt < 4; ++nt)
                s += fmaxf(C[mt][nt][r] + b1v[nt], 0.f) * w2v[nt];
            lsum[mt][r] = s;
        }
#pragma unroll
    for (int off = 1; off < 16; off <<= 1)
#pragma unroll
        for (int mt = 0; mt < 2; ++mt)
#pragma unroll
            for (int r = 0; r < 4; ++r)
                lsum[mt][r] += __shfl_xor(lsum[mt][r], off, 64);

    if (m16 == 0) {
#pragma unroll
        for (int mt = 0; mt < 2; ++mt) {
            f32x4 v;
#pragma unroll
            for (int r = 0; r < 4; ++r) v[r] = lsum[mt][r];
            *(f32x4*)&logitS[w * 32 + mt * 16 + quad * 4] = v;
        }
    }
    __syncthreads();

    // ---- softmax over k (32 rows of this wave's factor) ----
    const float lg = logitS[w * 32 + (lane & 31)];
    float mx = lg;
#pragma unroll
    for (int off = 16; off; off >>= 1) mx = fmaxf(mx, __shfl_xor(mx, off, 64));
    const float e = __expf(lg - mx);
    float s = e;
#pragma unroll
    for (int off = 16; off; off >>= 1) s += __shfl_xor(s, off, 64);
    const float wgt = e / s;   // weight for k = lane & 31

    // ---- output: out[f][d] = sum_k w_k * t[k][f][d] ----
    float oacc = 0.f;
#pragma unroll
    for (int k = 0; k < KK; ++k) {
        const float wk = __shfl(wgt, k, 64);
        oacc += wk * (float)Xs[(w * 32 + k) * XSTRIDE + w * FSKEW + 64 + lane];
    }
    out[(((size_t)(tower * 3 + 1 + layer) * BB + b) * NF + w) * DIM + lane] = oacc;

    // origin row (written once, by layer==0 blocks; exact f32 copy)
    if (layer == 0) {
        const int oid = idxarr[b];
        out[(((size_t)(tower * 3 + 0) * BB + b) * NF + w) * DIM + lane] =
            node_emb[((size_t)oid * NF + w) * DIM + lane];
    }
}

extern "C" void kernel_launch(void* const* d_in, const int* in_sizes, int n_in,
                              void* d_out, int out_size, void* d_ws, size_t ws_size,
                              hipStream_t stream) {
    const float* node_emb     = (const float*)d_in[0];
    // d_in[1] = relation_emb — dead in the reference computation
    const float* W1           = (const float*)d_in[2];
    const float* b1           = (const float*)d_in[3];
    const float* W2           = (const float*)d_in[4];
    const float* b2           = (const float*)d_in[5]; (void)b2; // cancels in softmax
    const int*   users        = (const int*)d_in[6];
    const int*   items        = (const int*)d_in[7];
    const int*   users_triple = (const int*)d_in[8];
    const int*   items_triple = (const int*)d_in[9];
    float* out = (float*)d_out;

    __bf16* w1t = (__bf16*)d_ws;                      // 16 KB
    __bf16* nbf = (__bf16*)((char*)d_ws + 16384);     // 102.4 MB bf16 node table
    // ws poison fill observed at 819.2 MB -> workspace comfortably holds nbf.

    hipLaunchKernelGGL(prep, dim3(NNODE * NF * DIM / 8 / 256), dim3(256), 0, stream,
                       node_emb, nbf, W1, w1t);
    hipLaunchKernelGGL(kgat_mfma, dim3(2 * BB * NLAYER), dim3(256), 0, stream,
                       nbf, node_emb, w1t, b1, W2,
                       users, items, users_triple, items_triple, out);
}

// Round 2
// 302.066 us; speedup vs baseline: 1.1515x; 1.1515x over previous
//
#include <hip/hip_runtime.h>
#include <hip/hip_bf16.h>
#include <math.h>

#define NNODE  200000
#define DIM    64
#define NF     4
#define NLAYER 2
#define KK     32
#define BB     1024

typedef __bf16 bf16x8 __attribute__((ext_vector_type(8)));
typedef __bf16 bf16x4 __attribute__((ext_vector_type(4)));
typedef float  f32x4  __attribute__((ext_vector_type(4)));

// X row stride in bf16 elements: 128 + 8 pad -> 272 B (16B-aligned, 2-way-only
// bank aliasing for the strided b128 fragment reads; 2-way is free per m136).
#define XSTRIDE 136

// Kernel 1: W1 (128x64 f32, row-major) -> W1T bf16 (64 x 128): w1t[d*128+i] = W1[i][d]
__global__ void prep_w1t(const float* __restrict__ W1, __bf16* __restrict__ w1t) {
    int j = blockIdx.x * 256 + threadIdx.x;   // 0..8191
    int d = j >> 7, i = j & 127;
    w1t[j] = (__bf16)W1[i * 64 + d];
}

// One block per (tower, b, layer). 256 threads = 4 waves; wave w = factor f.
// Per block: X = (128 rows (f*32+k) x 128 cols [h||t]) @ W1 (128x64) via MFMA.
__global__ __launch_bounds__(256, 2) void kgat_mfma(
    const float* __restrict__ node_emb,
    const __bf16* __restrict__ w1t,
    const float* __restrict__ b1,
    const float* __restrict__ W2,
    const int*   __restrict__ users,
    const int*   __restrict__ items,
    const int*   __restrict__ users_triple,
    const int*   __restrict__ items_triple,
    float*       __restrict__ out)
{
    __shared__ __bf16 Xs[128 * XSTRIDE];   // ~34 KB
    __shared__ float  logitS[128];

    const int bid   = blockIdx.x;          // 0..4095
    const int tower = bid >> 11;
    const int b     = (bid >> 1) & 1023;
    const int layer = bid & 1;
    const int tid   = threadIdx.x;
    const int w     = tid >> 6;            // wave id = factor
    const int lane  = tid & 63;
    const int m16   = lane & 15;
    const int quad  = lane >> 4;

    const int* __restrict__ triple = tower ? items_triple : users_triple;
    const int* __restrict__ idxarr = tower ? items : users;

    const int hbase = ((b * 3 + 0) * NLAYER + layer) * KK;
    const int tbase = ((b * 3 + 2) * NLAYER + layer) * KK;

    // ---- 1) Index loads FIRST: they gate the 16 gather addresses. ----
    const int m = tid & 15;
    const int g = tid >> 4;
    int kv[4], chv[4], idxv[4];
#pragma unroll
    for (int r = 0; r < 4; ++r) {
        const int task = r * 16 + g;            // 0..63
        kv[r]  = task & 31;
        chv[r] = task >> 5;                     // 0 = h, 1 = t
        idxv[r] = triple[(chv[r] ? tbase : hbase) + kv[r]];
    }

    // ---- 2) Origin-row load hoisted: issued now, consumed at the very end.
    // (one float per thread; avoids a cold ~900-cyc tail stall on layer==0) ----
    float origin_v = 0.f;
    if (layer == 0) {
        const int oid = idxarr[b];
        origin_v = node_emb[((size_t)oid * NF + w) * DIM + lane];
    }

    // ---- 3) B fragments (W1): L2-hot 16 KB; overlap the index-load latency.
    // B[k][n], n = nt*16 + m16, k = kt*32 + quad*8 + j. 64 VGPRs. ----
    bf16x8 Bf[4][4];
#pragma unroll
    for (int nt = 0; nt < 4; ++nt)
#pragma unroll
        for (int kt = 0; kt < 4; ++kt)
            Bf[nt][kt] = *(const bf16x8*)(w1t + (nt * 16 + m16) * 128 + kt * 32 + quad * 8);

    // ---- 4) Gather: 64 f32 row-gathers (32 h + 32 t), 1 KB each, -> bf16 LDS.
    // 16 threads/row, 16B/lane/instr; 16 independent loads in flight/thread. ----
#pragma unroll
    for (int r = 0; r < 4; ++r) {
        const float* __restrict__ src = node_emb + (size_t)idxv[r] * (NF * DIM);
#pragma unroll
        for (int j = 0; j < 4; ++j) {           // j = factor
            f32x4 v = *(const f32x4*)(src + j * 64 + m * 4);
            bf16x4 bv;
#pragma unroll
            for (int u = 0; u < 4; ++u) bv[u] = (__bf16)v[u];
            *(bf16x4*)(&Xs[(j * 32 + kv[r]) * XSTRIDE + chv[r] * 64 + m * 4]) = bv;
        }
    }
    __syncthreads();

    // ---- MFMA: wave w computes hid rows [w*32, w*32+32), all 64 cols ----
    f32x4 C[2][4];   // [m-tile][n-tile]
#pragma unroll
    for (int mt = 0; mt < 2; ++mt)
#pragma unroll
        for (int nt = 0; nt < 4; ++nt) C[mt][nt] = (f32x4)(0.f);

    const __bf16* Arow0 = &Xs[(w * 32 + m16) * XSTRIDE];        // m-tile 0
    const __bf16* Arow1 = &Xs[(w * 32 + 16 + m16) * XSTRIDE];   // m-tile 1
#pragma unroll
    for (int kt = 0; kt < 4; ++kt) {
        bf16x8 A0 = *(const bf16x8*)(Arow0 + kt * 32 + quad * 8);
        bf16x8 A1 = *(const bf16x8*)(Arow1 + kt * 32 + quad * 8);
#pragma unroll
        for (int nt = 0; nt < 4; ++nt) {
            C[0][nt] = __builtin_amdgcn_mfma_f32_16x16x32_bf16(A0, Bf[nt][kt], C[0][nt], 0, 0, 0);
            C[1][nt] = __builtin_amdgcn_mfma_f32_16x16x32_bf16(A1, Bf[nt][kt], C[1][nt], 0, 0, 0);
        }
    }

    // ---- Epilogue: logits[row] = sum_d relu(hid + b1) * W2  (b2 cancels) ----
    float b1v[4], w2v[4];
#pragma unroll
    for (int nt = 0; nt < 4; ++nt) {
        b1v[nt] = b1[nt * 16 + m16];
        w2v[nt] = W2[nt * 16 + m16];
    }
    float lsum[2][4];   // [mt][reg]; C row = mt*16 + quad*4 + reg, col = nt*16 + m16
#pragma unroll
    for (int mt = 0; mt < 2; ++mt)
#pragma unroll
        for (int r = 0; r < 4; ++r) {
            float s = 0.f;
#pragma unroll
            for (int nt = 0; nt < 4; ++nt)
                s += fmaxf(C[mt][nt][r] + b1v[nt], 0.f) * w2v[nt];
            lsum[mt][r] = s;
        }
    // reduce across the 16 column-lanes (lane bits 0..3)
#pragma unroll
    for (int off = 1; off < 16; off <<= 1)
#pragma unroll
        for (int mt = 0; mt < 2; ++mt)
#pragma unroll
            for (int r = 0; r < 4; ++r)
                lsum[mt][r] += __shfl_xor(lsum[mt][r], off, 64);

    if (m16 == 0) {
#pragma unroll
        for (int mt = 0; mt < 2; ++mt) {
            f32x4 v;
#pragma unroll
            for (int r = 0; r < 4; ++r) v[r] = lsum[mt][r];
            *(f32x4*)&logitS[w * 32 + mt * 16 + quad * 4] = v;
        }
    }
    __syncthreads();

    // ---- softmax over k (32 rows of this wave's factor) ----
    const float lg = logitS[w * 32 + (lane & 31)];
    float mx = lg;
#pragma unroll
    for (int off = 16; off; off >>= 1) mx = fmaxf(mx, __shfl_xor(mx, off, 64));
    const float e = __expf(lg - mx);
    float s = e;
#pragma unroll
    for (int off = 16; off; off >>= 1) s += __shfl_xor(s, off, 64);
    const float wgt = e / s;   // weight for k = lane & 31

    // ---- output: out[f][d] = sum_k w_k * t[k][f][d]  (t read back from LDS bf16) ----
    float oacc = 0.f;
#pragma unroll
    for (int k = 0; k < KK; ++k) {
        const float wk = __shfl(wgt, k, 64);
        oacc += wk * (float)Xs[(w * 32 + k) * XSTRIDE + 64 + lane];
    }
    out[(((size_t)(tower * 3 + 1 + layer) * BB + b) * NF + w) * DIM + lane] = oacc;

    // origin row (written once, by layer==0 blocks; load was issued at the top)
    if (layer == 0) {
        out[(((size_t)(tower * 3 + 0) * BB + b) * NF + w) * DIM + lane] = origin_v;
    }
}

extern "C" void kernel_launch(void* const* d_in, const int* in_sizes, int n_in,
                              void* d_out, int out_size, void* d_ws, size_t ws_size,
                              hipStream_t stream) {
    const float* node_emb     = (const float*)d_in[0];
    // d_in[1] = relation_emb — dead in the reference computation
    const float* W1           = (const float*)d_in[2];
    const float* b1           = (const float*)d_in[3];
    const float* W2           = (const float*)d_in[4];
    const float* b2           = (const float*)d_in[5]; (void)b2; // cancels in softmax
    const int*   users        = (const int*)d_in[6];
    const int*   items        = (const int*)d_in[7];
    const int*   users_triple = (const int*)d_in[8];
    const int*   items_triple = (const int*)d_in[9];
    float* out = (float*)d_out;

    __bf16* w1t = (__bf16*)d_ws;   // 64*128*2 = 16 KB

    hipLaunchKernelGGL(prep_w1t, dim3(32), dim3(256), 0, stream, W1, w1t);
    hipLaunchKernelGGL(kgat_mfma, dim3(2 * BB * NLAYER), dim3(256), 0, stream,
                       node_emb, w1t, b1, W2,
                       users, items, users_triple, items_triple, out);
}

// Round 3
// 296.318 us; speedup vs baseline: 1.1738x; 1.0194x over previous
//
#include <hip/hip_runtime.h>
#include <hip/hip_bf16.h>
#include <math.h>

#define NNODE  200000
#define DIM    64
#define NF     4
#define NLAYER 2
#define KK     32
#define BB     1024

typedef __bf16 bf16x8 __attribute__((ext_vector_type(8)));
typedef __bf16 bf16x4 __attribute__((ext_vector_type(4)));
typedef float  f32x4  __attribute__((ext_vector_type(4)));

// X row stride in bf16 elements: 128 + 8 pad -> 272 B (16B-aligned, 2-way-only
// bank aliasing for the strided b128 fragment reads; 2-way is free per m136).
#define XSTRIDE 136
// W1T LDS stride (same padding logic: row stride 272 B -> fragment reads that
// vary m16 across 16 lanes land on banks m16*4 mod 32 -> 2-way = free).
#define WSTRIDE 136

// Single kernel. One block per (tower, b, layer). 256 threads = 4 waves;
// wave w = factor f. Per block: X = (128 rows x 128 cols [h||t]) @ W1 via MFMA.
// LDS: 34.8 KB (Xs) + 17.4 KB (W1s) + 0.5 KB = 52.7 KB -> 3 blocks/CU.
__global__ __launch_bounds__(256, 3) void kgat_mfma(
    const float* __restrict__ node_emb,
    const float* __restrict__ W1,
    const float* __restrict__ b1,
    const float* __restrict__ W2,
    const int*   __restrict__ users,
    const int*   __restrict__ items,
    const int*   __restrict__ users_triple,
    const int*   __restrict__ items_triple,
    float*       __restrict__ out)
{
    __shared__ __bf16 Xs[128 * XSTRIDE];     // 34816 B
    __shared__ __bf16 W1s[64 * WSTRIDE];     // 17408 B  (W1T: [d][i], bf16)
    __shared__ float  logitS[128];

    const int bid   = blockIdx.x;          // 0..4095
    const int tower = bid >> 11;
    const int b     = (bid >> 1) & 1023;
    const int layer = bid & 1;
    const int tid   = threadIdx.x;
    const int w     = tid >> 6;            // wave id = factor
    const int lane  = tid & 63;
    const int m16   = lane & 15;
    const int quad  = lane >> 4;

    const int* __restrict__ triple = tower ? items_triple : users_triple;
    const int* __restrict__ idxarr = tower ? items : users;

    const int hbase = ((b * 3 + 0) * NLAYER + layer) * KK;
    const int tbase = ((b * 3 + 2) * NLAYER + layer) * KK;

    // ---- 1) Index loads FIRST: they gate the 16 gather addresses. ----
    const int m = tid & 15;
    const int g = tid >> 4;
    int kv[4], chv[4], idxv[4];
#pragma unroll
    for (int r = 0; r < 4; ++r) {
        const int task = r * 16 + g;            // 0..63
        kv[r]  = task & 31;
        chv[r] = task >> 5;                     // 0 = h, 1 = t
        idxv[r] = triple[(chv[r] ? tbase : hbase) + kv[r]];
    }

    // ---- 2) Origin-row load hoisted: issued now, consumed at the very end. ----
    float origin_v = 0.f;
    if (layer == 0) {
        const int oid = idxarr[b];
        origin_v = node_emb[((size_t)oid * NF + w) * DIM + lane];
    }

    // ---- 3) W1 stage: 128x64 f32 (32 KB, L2-hot) -> W1T bf16 in LDS.
    // 32 elems/thread as 8 x f32x4; W1s[d][i] = (bf16)W1[i][d]. Overlaps the
    // index-load latency; same RNE cast as the old prep_w1t kernel. ----
#pragma unroll
    for (int it = 0; it < 8; ++it) {
        const int p = (it * 256 + tid) * 4;     // linear f32 index, 4 | 64
        const int i = p >> 6, d = p & 63;
        f32x4 v = *(const f32x4*)(W1 + p);
#pragma unroll
        for (int u = 0; u < 4; ++u)
            W1s[(d + u) * WSTRIDE + i] = (__bf16)v[u];
    }

    // ---- 4) Gather: 64 f32 row-gathers (32 h + 32 t), 1 KB each, -> bf16 LDS.
    // 16 threads/row, 16B/lane/instr; 16 independent loads in flight/thread. ----
#pragma unroll
    for (int r = 0; r < 4; ++r) {
        const float* __restrict__ src = node_emb + (size_t)idxv[r] * (NF * DIM);
#pragma unroll
        for (int j = 0; j < 4; ++j) {           // j = factor
            f32x4 v = *(const f32x4*)(src + j * 64 + m * 4);
            bf16x4 bv;
#pragma unroll
            for (int u = 0; u < 4; ++u) bv[u] = (__bf16)v[u];
            *(bf16x4*)(&Xs[(j * 32 + kv[r]) * XSTRIDE + chv[r] * 64 + m * 4]) = bv;
        }
    }
    __syncthreads();

    // ---- 5) B fragments from LDS: B[k][n], n = nt*16+m16, k = kt*32+quad*8+j ----
    bf16x8 Bf[4][4];
#pragma unroll
    for (int nt = 0; nt < 4; ++nt)
#pragma unroll
        for (int kt = 0; kt < 4; ++kt)
            Bf[nt][kt] = *(const bf16x8*)(&W1s[(nt * 16 + m16) * WSTRIDE + kt * 32 + quad * 8]);

    // ---- MFMA: wave w computes hid rows [w*32, w*32+32), all 64 cols ----
    f32x4 C[2][4];   // [m-tile][n-tile]
#pragma unroll
    for (int mt = 0; mt < 2; ++mt)
#pragma unroll
        for (int nt = 0; nt < 4; ++nt) C[mt][nt] = (f32x4)(0.f);

    const __bf16* Arow0 = &Xs[(w * 32 + m16) * XSTRIDE];        // m-tile 0
    const __bf16* Arow1 = &Xs[(w * 32 + 16 + m16) * XSTRIDE];   // m-tile 1
#pragma unroll
    for (int kt = 0; kt < 4; ++kt) {
        bf16x8 A0 = *(const bf16x8*)(Arow0 + kt * 32 + quad * 8);
        bf16x8 A1 = *(const bf16x8*)(Arow1 + kt * 32 + quad * 8);
#pragma unroll
        for (int nt = 0; nt < 4; ++nt) {
            C[0][nt] = __builtin_amdgcn_mfma_f32_16x16x32_bf16(A0, Bf[nt][kt], C[0][nt], 0, 0, 0);
            C[1][nt] = __builtin_amdgcn_mfma_f32_16x16x32_bf16(A1, Bf[nt][kt], C[1][nt], 0, 0, 0);
        }
    }

    // ---- Epilogue: logits[row] = sum_d relu(hid + b1) * W2  (b2 cancels) ----
    float b1v[4], w2v[4];
#pragma unroll
    for (int nt = 0; nt < 4; ++nt) {
        b1v[nt] = b1[nt * 16 + m16];
        w2v[nt] = W2[nt * 16 + m16];
    }
    float lsum[2][4];   // [mt][reg]; C row = mt*16 + quad*4 + reg, col = nt*16 + m16
#pragma unroll
    for (int mt = 0; mt < 2; ++mt)
#pragma unroll
        for (int r = 0; r < 4; ++r) {
            float s = 0.f;
#pragma unroll
            for (int nt = 0; nt < 4; ++nt)
                s += fmaxf(C[mt][nt][r] + b1v[nt], 0.f) * w2v[nt];
            lsum[mt][r] = s;
        }
    // reduce across the 16 column-lanes (lane bits 0..3)
#pragma unroll
    for (int off = 1; off < 16; off <<= 1)
#pragma unroll
        for (int mt = 0; mt < 2; ++mt)
#pragma unroll
            for (int r = 0; r < 4; ++r)
                lsum[mt][r] += __shfl_xor(lsum[mt][r], off, 64);

    if (m16 == 0) {
#pragma unroll
        for (int mt = 0; mt < 2; ++mt) {
            f32x4 v;
#pragma unroll
            for (int r = 0; r < 4; ++r) v[r] = lsum[mt][r];
            *(f32x4*)&logitS[w * 32 + mt * 16 + quad * 4] = v;
        }
    }
    __syncthreads();

    // ---- softmax over k (32 rows of this wave's factor) ----
    const float lg = logitS[w * 32 + (lane & 31)];
    float mx = lg;
#pragma unroll
    for (int off = 16; off; off >>= 1) mx = fmaxf(mx, __shfl_xor(mx, off, 64));
    const float e = __expf(lg - mx);
    float s = e;
#pragma unroll
    for (int off = 16; off; off >>= 1) s += __shfl_xor(s, off, 64);
    const float wgt = e / s;   // weight for k = lane & 31

    // ---- output: out[f][d] = sum_k w_k * t[k][f][d]  (t read back from LDS bf16) ----
    float oacc = 0.f;
#pragma unroll
    for (int k = 0; k < KK; ++k) {
        const float wk = __shfl(wgt, k, 64);
        oacc += wk * (float)Xs[(w * 32 + k) * XSTRIDE + 64 + lane];
    }
    out[(((size_t)(tower * 3 + 1 + layer) * BB + b) * NF + w) * DIM + lane] = oacc;

    // origin row (written once, by layer==0 blocks; load was issued at the top)
    if (layer == 0) {
        out[(((size_t)(tower * 3 + 0) * BB + b) * NF + w) * DIM + lane] = origin_v;
    }
}

extern "C" void kernel_launch(void* const* d_in, const int* in_sizes, int n_in,
                              void* d_out, int out_size, void* d_ws, size_t ws_size,
                              hipStream_t stream) {
    const float* node_emb     = (const float*)d_in[0];
    // d_in[1] = relation_emb — dead in the reference computation
    const float* W1           = (const float*)d_in[2];
    const float* b1           = (const float*)d_in[3];
    const float* W2           = (const float*)d_in[4];
    const float* b2           = (const float*)d_in[5]; (void)b2; // cancels in softmax
    const int*   users        = (const int*)d_in[6];
    const int*   items        = (const int*)d_in[7];
    const int*   users_triple = (const int*)d_in[8];
    const int*   items_triple = (const int*)d_in[9];
    float* out = (float*)d_out;
    (void)d_ws; (void)ws_size;

    hipLaunchKernelGGL(kgat_mfma, dim3(2 * BB * NLAYER), dim3(256), 0, stream,
                       node_emb, W1, b1, W2,
                       users, items, users_triple, items_triple, out);
}